// Round 7
// baseline (1256.478 us; speedup 1.0000x reference)
//
#include <hip/hip_runtime.h>

#define J 27
#define D 512
#define H 8
#define DH 64
#define NLAYER 6
#define DFF 2048
#define NB 64
#define NP 2048
#define CAP 128
#define GCH 16
#define GPTS 128
#define NEGF -1000000000.0f

typedef unsigned short u16;
typedef __attribute__((ext_vector_type(8))) __bf16 bf16x8;
typedef __attribute__((ext_vector_type(4))) float f32x4;

__constant__ int c_parent[J] = {0,0,1,2,3,4,5,6,7,8,8,3,11,12,13,14,15,15,0,18,19,20,0,22,23,24,3};
__constant__ float c_scale[J] = {0.6f,0.6f,0.6f,0.6f,1.f,1.f,1.f,1.f,1.f,1.5f,1.5f,1.f,1.f,1.f,1.f,1.f,
                                 1.5f,1.5f,0.6f,1.f,1.5f,1.5f,0.6f,1.f,1.5f,1.5f,1.5f};

__device__ __forceinline__ float siluf(float x){ return x/(1.f+expf(-x)); }

__device__ __forceinline__ u16 f2bf(float f){
  union { float f; unsigned u; } x; x.f = f;
  unsigned r = x.u + 0x7FFFu + ((x.u >> 16) & 1u);
  return (u16)(r >> 16);
}

// ---------- per (b,j): denom sum, rescue idx, allmask, active-bitmap marks ----------
__global__ void k_perj(const float* __restrict__ x_t, const float* __restrict__ pc,
                       float* __restrict__ denom_sum, int* __restrict__ rescue,
                       int* __restrict__ allm, unsigned int* __restrict__ bitmap){
  int bj = blockIdx.x; int b = bj / J, j = bj % J;
  int t = threadIdx.x;
  float x0 = x_t[(b*J+j)*3+0];
  float x1 = x_t[(b*J+j)*3+1];
  float x2 = x_t[(b*J+j)*3+2];
  float sx = x0*x0+x1*x1+x2*x2;
  float ar = c_scale[j]*0.1f;
  float sig = ar*0.5f;
  float twos2 = 2.f*sig*sig;
  float sum = 0.f, bmin = 3.4e38f; int bidx = NP; int any = 0;
  for (int n = t; n < NP; n += 256){
    const float* p = pc + ((size_t)b*NP + n)*6;
    float p0=p[0], p1=p[1], p2=p[2];
    float d2 = sx + (p0*p0+p1*p1+p2*p2) - 2.f*(x0*p0+x1*p1+x2*p2);
    float dist = sqrtf(fmaxf(d2, 0.f));
    sum += expf(-(dist*dist)/twos2);
    if (dist < bmin){ bmin = dist; bidx = n; }
    if (dist <= ar){ any = 1; atomicOr(&bitmap[b*(NP/32)+(n>>5)], 1u<<(n&31)); }
  }
  __shared__ float ssum[256]; __shared__ float smin[256];
  __shared__ int sidx[256]; __shared__ int sany[256];
  ssum[t]=sum; smin[t]=bmin; sidx[t]=bidx; sany[t]=any;
  __syncthreads();
  for (int s = 128; s > 0; s >>= 1){
    if (t < s){
      ssum[t] += ssum[t+s];
      if (smin[t+s] < smin[t] || (smin[t+s]==smin[t] && sidx[t+s] < sidx[t])){ smin[t]=smin[t+s]; sidx[t]=sidx[t+s]; }
      sany[t] |= sany[t+s];
    }
    __syncthreads();
  }
  if (t == 0){
    denom_sum[bj] = ssum[0];
    rescue[bj] = sidx[0];
    allm[bj] = sany[0] ? 0 : 1;
    if (!sany[0]) atomicOr(&bitmap[b*(NP/32)+(sidx[0]>>5)], 1u<<(sidx[0]&31));
  }
}

// ---------- ordered compaction of active bitmap ----------
__global__ void k_compact(const unsigned int* __restrict__ bitmap, int* __restrict__ act_idx,
                          int* __restrict__ act_cnt){
  int b = blockIdx.x; int t = threadIdx.x; // 64 = 1 wave
  unsigned int w = bitmap[b*(NP/32)+t];
  int c = __popc(w);
  int off = c;
  for (int s = 1; s < 64; s <<= 1){
    int v = __shfl_up(off, s);
    if (t >= s) off += v;
  }
  int total = __shfl(off, 63);
  off -= c;
  int base = off;
  for (int bit = 0; bit < 32; ++bit){
    if (w & (1u<<bit)){
      if (base < CAP) act_idx[b*CAP+base] = t*32+bit;
      base++;
    }
  }
  if (t == 0) act_cnt[b] = total > CAP ? CAP : total;
}

__global__ void k_scan(const int* __restrict__ act_cnt, int* __restrict__ act_off,
                       int* __restrict__ act_total){
  if (threadIdx.x == 0){
    int s = 0;
    for (int b = 0; b < NB; ++b){ act_off[b] = s; s += act_cnt[b]; }
    act_total[0] = s;
  }
}

// ---------- G[b,ch,j,h] = sum_p dws[b,j,p] * silu(dop*w1[h]+b1[h])  via MFMA ----------
__launch_bounds__(256)
__global__ void k_gpart(const float* __restrict__ x_t, const float* __restrict__ pc,
                        const float* __restrict__ dop_w1, const float* __restrict__ dop_b1,
                        float* __restrict__ Gp){
  int b = blockIdx.x, ch = blockIdx.y; int t = threadIdx.x;
  __shared__ float sx[J*3];
  __shared__ float w1s[64], b1s[64];
  __shared__ float spx[GPTS], spy[GPTS], spz[GPTS], sdp[GPTS];
  __shared__ u16 hidT[64*128];
  __shared__ u16 dwsA[32*128];
  if (t < J*3) sx[t] = x_t[b*J*3 + t];
  if (t < 64){ w1s[t] = dop_w1[t]; b1s[t] = dop_b1[t]; }
  int n0 = ch*GPTS;
  if (t < GPTS){
    const float* p = pc + ((size_t)b*NP + n0 + t)*6;
    float2 f0 = *(const float2*)p;
    float2 f1 = *(const float2*)(p+2);
    spx[t]=f0.x; spy[t]=f0.y; spz[t]=f1.x; sdp[t]=f1.y;
  }
  __syncthreads();
  {
    int h = t & 63, pb = (t>>6)*32;
    float w1 = w1s[h], b1 = b1s[h];
    char* base = (char*)hidT;
    #pragma unroll
    for (int m = 0; m < 16; ++m){
      float v0 = siluf(sdp[pb+2*m]*w1 + b1);
      float v1 = siluf(sdp[pb+2*m+1]*w1 + b1);
      unsigned pk = (unsigned)f2bf(v0) | ((unsigned)f2bf(v1) << 16);
      int off = (h*256 + pb*2 + 4*m) ^ ((h&7)<<4);
      *(unsigned*)(base + off) = pk;
    }
  }
  {
    int j = t & 31, pb = (t>>5)*16;
    if (j < J){
      float x0=sx[j*3], x1=sx[j*3+1], x2=sx[j*3+2];
      float sxx = x0*x0+x1*x1+x2*x2;
      float sig = c_scale[j]*0.05f;
      float inv2 = 1.f/(2.f*sig*sig);
      char* base = (char*)dwsA;
      #pragma unroll
      for (int m = 0; m < 8; ++m){
        float v[2];
        #pragma unroll
        for (int u = 0; u < 2; ++u){
          int p = pb + 2*m + u;
          float p0=spx[p], p1=spy[p], p2=spz[p];
          float d2 = sxx + (p0*p0+p1*p1+p2*p2) - 2.f*(x0*p0+x1*p1+x2*p2);
          float dist = sqrtf(fmaxf(d2, 0.f));
          v[u] = expf(-(dist*dist)*inv2);
        }
        unsigned pk = (unsigned)f2bf(v[0]) | ((unsigned)f2bf(v[1]) << 16);
        int off = (j*256 + pb*2 + 4*m) ^ ((j&7)<<4);
        *(unsigned*)(base + off) = pk;
      }
    }
  }
  __syncthreads();
  int lane = t & 63, wv = t >> 6;
  int h0 = wv * 16;
  int fr = lane & 15, fkb = (lane>>4)*16;
  f32x4 acc[2] = {};
  #pragma unroll
  for (int ks = 0; ks < 4; ++ks){
    bf16x8 bfrag;
    {
      int row = h0 + fr;
      int adr = (row*256 + ks*64 + fkb) ^ ((row&7)<<4);
      bfrag = *(const bf16x8*)((char*)hidT + adr);
    }
    #pragma unroll
    for (int m = 0; m < 2; ++m){
      int row = m*16 + fr;
      int adr = (row*256 + ks*64 + fkb) ^ ((row&7)<<4);
      bf16x8 afrag = *(const bf16x8*)((char*)dwsA + adr);
      acc[m] = __builtin_amdgcn_mfma_f32_16x16x32_bf16(afrag, bfrag, acc[m], 0,0,0);
    }
  }
  float* out = Gp + ((size_t)(b*GCH+ch))*J*64;
  int er = (lane>>4)*4, ec = lane&15;
  #pragma unroll
  for (int m = 0; m < 2; ++m){
    #pragma unroll
    for (int q = 0; q < 4; ++q){
      int j = m*16 + er + q;
      if (j < J) out[j*64 + h0 + ec] = acc[m][q];
    }
  }
}

// ---------- h_dop: chunk-reduce Gp inline; one block per (b, d-half) ----------
__launch_bounds__(256)
__global__ void k_hdop2(const float* __restrict__ Gp, const float* __restrict__ dop_w2,
                        const float* __restrict__ dop_b2, const float* __restrict__ denom_sum,
                        float* __restrict__ h_dop){
  int b = blockIdx.x, half = blockIdx.y;
  int t = threadIdx.x;
  int d = half*256 + t;
  __shared__ float sG[J*64];
  __shared__ float sS[J], sI[J];
  for (int e = t; e < J*64; e += 256){
    float s = 0.f;
    #pragma unroll
    for (int c = 0; c < GCH; ++c) s += Gp[(size_t)(b*GCH+c)*J*64 + e];
    sG[e] = s;
  }
  if (t < J){ float S = denom_sum[b*J+t]; sS[t] = S; sI[t] = 1.f/(S+1e-6f); }
  __syncthreads();
  float acc[J];
  #pragma unroll
  for (int j = 0; j < J; ++j) acc[j] = 0.f;
  for (int h = 0; h < 64; ++h){
    float wv = dop_w2[h*D + d];
    #pragma unroll
    for (int j = 0; j < J; ++j) acc[j] += sG[j*64+h]*wv;
  }
  float b2 = dop_b2[d];
  #pragma unroll
  for (int j = 0; j < J; ++j)
    h_dop[(size_t)(b*J+j)*D + d] = (acc[j] + sS[j]*b2)*sI[j];
}

// ---------- merged stage-1 elementwise ----------
__global__ void k_stage1(const float* __restrict__ x_t, const float* __restrict__ state_w,
                         const float* __restrict__ state_b,
                         const float* __restrict__ coarse, const float* __restrict__ coarse_w,
                         const float* __restrict__ coarse_b,
                         const float* __restrict__ t_in, const float* __restrict__ time_w1,
                         const float* __restrict__ time_b1,
                         float* __restrict__ h_state, u16* __restrict__ hsh,
                         float* __restrict__ h_coarse, u16* __restrict__ thh){
  const int RD = NB*J*D;
  int idx = blockIdx.x*256 + threadIdx.x;
  if (idx < RD){
    int r = idx / D, d = idx % D;
    const float* ir = x_t + r*3;
    float v = ir[0]*state_w[d] + ir[1]*state_w[D+d] + ir[2]*state_w[2*D+d] + state_b[d];
    h_state[idx] = v;
    hsh[idx] = f2bf(v);
  } else if (idx < 2*RD){
    int k = idx - RD;
    int r = k / D, d = k % D;
    const float* ir = coarse + r*3;
    h_coarse[k] = ir[0]*coarse_w[d] + ir[1]*coarse_w[D+d] + ir[2]*coarse_w[2*D+d] + coarse_b[d];
  } else if (idx < 2*RD + NB*D){
    int k = idx - 2*RD;
    int b = k / D, d = k % D;
    float v = siluf(t_in[b]*time_w1[d] + time_b1[d]);
    thh[k] = f2bf(v);
  }
}

__global__ void k_hs2(const float* __restrict__ h_state, u16* __restrict__ oh){
  int idx = blockIdx.x*256 + threadIdx.x;
  if (idx >= NB*J*2*D) return;
  int r = idx / (2*D), c = idx % (2*D);
  int b = r / J, j = r % J;
  float v;
  if (c < D) v = h_state[(size_t)r*D + c];
  else       v = h_state[((size_t)(b*J) + c_parent[j])*D + (c-D)];
  oh[idx] = f2bf(v);
}

__global__ void k_query(const float* __restrict__ h_coarse, const float* __restrict__ h_time,
                        const float* __restrict__ h_dop, const float* __restrict__ h_state,
                        const float* __restrict__ hstruct, const float* __restrict__ jid,
                        const float* __restrict__ mod2, float* __restrict__ x){
  int idx = blockIdx.x*256 + threadIdx.x;
  if (idx >= NB*J*D) return;
  int r = idx / D, d = idx % D;
  int b = r / J, j = r % J;
  float q = h_coarse[idx] + h_time[b*D+d] + h_dop[idx] + h_state[idx] + hstruct[idx] + jid[j*D+d];
  float shift = mod2[(size_t)r*2*D + d];
  float scale = mod2[(size_t)r*2*D + D + d];
  x[idx] = q*(1.f+scale) + shift;
}

// ---------- memory rows for active points (bf16) ----------
__global__ void k_memact(const float* __restrict__ x_t, const float* __restrict__ pc,
                         const float* __restrict__ pc_w, const float* __restrict__ pc_b,
                         const int* __restrict__ act_idx, const int* __restrict__ act_cnt,
                         const int* __restrict__ act_off, u16* __restrict__ mh){
  int b = blockIdx.x / CAP, i = blockIdx.x % CAP;
  if (i >= act_cnt[b]) return;
  int n = act_idx[b*CAP+i];
  int t = threadIdx.x; // 128
  __shared__ float sdw[J];
  __shared__ float spi;
  const float* p = pc + ((size_t)b*NP+n)*6;
  if (t < J){
    float x0 = x_t[(b*J+t)*3+0], x1 = x_t[(b*J+t)*3+1], x2 = x_t[(b*J+t)*3+2];
    float p0=p[0], p1=p[1], p2=p[2];
    float d2 = (x0*x0+x1*x1+x2*x2) + (p0*p0+p1*p1+p2*p2) - 2.f*(x0*p0+x1*p1+x2*p2);
    float dist = sqrtf(fmaxf(d2,0.f));
    float sig = c_scale[t]*0.05f;
    sdw[t] = expf(-(dist*dist)/(2.f*sig*sig));
  }
  __syncthreads();
  if (t == 0){ float m = sdw[0]; for (int k = 1; k < J; ++k) m = fmaxf(m, sdw[k]); spi = m; }
  __syncthreads();
  float pi = spi;
  float p0=p[0],p1=p[1],p2=p[2],p3=p[3],p4=p[4],p5=p[5];
  int g = act_off[b] + i;
  for (int d = t; d < D; d += 128){
    float acc = pc_b[d] + p0*pc_w[d] + p1*pc_w[D+d] + p2*pc_w[2*D+d]
              + p3*pc_w[3*D+d] + p4*pc_w[4*D+d] + p5*pc_w[5*D+d];
    mh[(size_t)g*D + d] = f2bf(acc * pi);
  }
}

// ---------- single-launch weight conversion: W[K][N] fp32 -> Wt[N][K] bf16 ----------
struct WcD { const float* src; u16* dst; int K; int N; int tk; int tn; int L; int start; };
struct WcTab { WcD d[10]; };
__launch_bounds__(256)
__global__ void k_wconv_all(WcTab tab){
  int tid = blockIdx.x;
  WcD w = tab.d[0];
  #pragma unroll
  for (int i = 0; i < 10; ++i){
    int end = tab.d[i].start + tab.d[i].tk*tab.d[i].tn*tab.d[i].L;
    if (tid >= tab.d[i].start && tid < end) w = tab.d[i];
  }
  int local = tid - w.start;
  int per = w.tk*w.tn;
  int l = local / per, rem = local % per;
  int k0 = (rem % w.tk)*64, n0 = (rem / w.tk)*64;
  size_t zo = (size_t)l*w.K*w.N;
  __shared__ float tile[64][65];
  int t = threadIdx.x;
  #pragma unroll
  for (int i = 0; i < 16; ++i){
    int idx = i*256 + t; int k = idx>>6, n = idx&63;
    tile[k][n] = w.src[zo + (size_t)(k0+k)*w.N + n0+n];
  }
  __syncthreads();
  #pragma unroll
  for (int i = 0; i < 8; ++i){
    int idx = i*256 + t; int n = idx>>5, kp = (idx&31)*2;
    unsigned pk = (unsigned)f2bf(tile[kp][n]) | ((unsigned)f2bf(tile[kp+1][n])<<16);
    *(unsigned*)&w.dst[zo + (size_t)(n0+n)*w.K + k0+kp] = pk;
  }
}

// ---------- MFMA GEMM core: C = act(Abf16 @ Wbf16 + bias [+ res]) ----------
// double-buffered LDS, ONE barrier per K-step. A [M][K] bf16; B [N][K] bf16.
struct GemmArgs {
  const u16* Ag; const u16* Bt; const float* bias; const float* res;
  float* Cf; u16* Ch; int M, N, K, act; const int* Mdev; int ntx; int nwg;
};

template<int TM>
__device__ __forceinline__ void gemm_body(const GemmArgs g, int bid, char* smem){
  int Meff = g.Mdev ? *g.Mdev : g.M;
  int q8 = g.nwg>>3, r8 = g.nwg&7;
  int xcd = bid&7, loc = bid>>3;
  int wg = (xcd < r8 ? xcd*(q8+1) : r8*(q8+1)+(xcd-r8)*q8) + loc;
  int row0 = (wg % g.ntx)*TM, col0 = (wg / g.ntx)*64;
  if (row0 >= Meff) return;
  constexpr int ABUF = TM*64*2;
  constexpr int BBUF = 64*64*2;
  char* sAb[2] = { smem, smem + ABUF };
  char* sBb[2] = { smem + 2*ABUF, smem + 2*ABUF + BBUF };
  int t = threadIdx.x;
  int lane = t&63, w = t>>6, wr = w>>1, wc = w&1;
  int sm = t>>3, kc = t&7;
  int K = g.K, N = g.N;
  const u16* pA1 = g.Ag + (size_t)(row0+sm)*K + kc*8;
  const u16* pA2 = (TM==64) ? g.Ag + (size_t)(row0+sm+32)*K + kc*8 : pA1;
  const u16* pB1 = g.Bt + (size_t)(col0+sm)*K + kc*8;
  const u16* pB2 = g.Bt + (size_t)(col0+sm+32)*K + kc*8;
  int o1 = (sm*128 + kc*16) ^ ((sm&7)<<4);
  int o2 = ((sm+32)*128 + kc*16) ^ ((sm&7)<<4);
  uint4 ra1, ra2, rb1, rb2;
  auto gload = [&](int kt){
    ra1 = *(const uint4*)(pA1 + kt);
    if constexpr (TM==64) ra2 = *(const uint4*)(pA2 + kt);
    rb1 = *(const uint4*)(pB1 + kt);
    rb2 = *(const uint4*)(pB2 + kt);
  };
  auto stage = [&](int bf_){
    *(uint4*)(sAb[bf_] + o1) = ra1;
    if constexpr (TM==64) *(uint4*)(sAb[bf_] + o2) = ra2;
    *(uint4*)(sBb[bf_] + o1) = rb1;
    *(uint4*)(sBb[bf_] + o2) = rb2;
  };
  constexpr int MFR = TM/32;
  constexpr int RW  = TM/2;
  int fr = lane&15, fkb = (lane>>4)*16;
  f32x4 acc[MFR][2] = {};
  gload(0);
  stage(0);
  __syncthreads();
  int cur = 0;
  for (int kt = 0; kt < K; kt += 64){
    bool nxt = kt + 64 < K;
    if (nxt) gload(kt + 64);   // latency hides under compute
    #pragma unroll
    for (int kk = 0; kk < 2; ++kk){
      bf16x8 af[MFR], bf[2];
      #pragma unroll
      for (int m = 0; m < MFR; ++m){
        int row = wr*RW + m*16 + fr;
        int adr = (row*128 + kk*64 + fkb) ^ ((row&7)<<4);
        af[m] = *(const bf16x8*)(sAb[cur] + adr);
      }
      #pragma unroll
      for (int n = 0; n < 2; ++n){
        int rowb = wc*32 + n*16 + fr;
        int adr = (rowb*128 + kk*64 + fkb) ^ ((rowb&7)<<4);
        bf[n] = *(const bf16x8*)(sBb[cur] + adr);
      }
      #pragma unroll
      for (int m = 0; m < MFR; ++m)
        #pragma unroll
        for (int n = 0; n < 2; ++n)
          acc[m][n] = __builtin_amdgcn_mfma_f32_16x16x32_bf16(af[m], bf[n], acc[m][n], 0,0,0);
    }
    if (nxt){
      stage(cur^1);        // different buffer: no conflict with in-flight reads
      __syncthreads();     // one barrier per K-step
      cur ^= 1;
    }
  }
  int er = (lane>>4)*4, ec = lane&15;
  #pragma unroll
  for (int m = 0; m < MFR; ++m){
    #pragma unroll
    for (int qq = 0; qq < 4; ++qq){
      int r = row0 + wr*RW + m*16 + er + qq;
      if (r >= Meff) continue;
      #pragma unroll
      for (int n = 0; n < 2; ++n){
        int c = col0 + wc*32 + n*16 + ec;
        float v = acc[m][n][qq] + g.bias[c];
        if (g.res) v += g.res[(size_t)r*N + c];
        if (g.act == 1) v = v/(1.f+expf(-v));
        else if (g.act == 2) v = fmaxf(v, 0.f);
        if (g.Cf) g.Cf[(size_t)r*N + c] = v;
        if (g.Ch) g.Ch[(size_t)r*N + c] = f2bf(v);
      }
    }
  }
}

template<int TM>
__launch_bounds__(256)
__global__ void k_gemm(GemmArgs g){
  constexpr int SZ = 2*(TM*64*2) + 2*(64*64*2);
  __shared__ __align__(16) char smem[SZ];
  gemm_body<TM>(g, blockIdx.x, smem);
}

// ca_q (TM=32) and kv (TM=64) merged into one launch
__launch_bounds__(256)
__global__ void k_gemm_dual(GemmArgs ga, GemmArgs gb){
  __shared__ __align__(16) char smem[32768];
  if ((int)blockIdx.x < ga.nwg) gemm_body<32>(ga, blockIdx.x, smem);
  else                          gemm_body<64>(gb, blockIdx.x - ga.nwg, smem);
}

// ---------- LayerNorm over D, per row -> bf16 ----------
__global__ void k_ln(const float* __restrict__ x, const float* __restrict__ s,
                     const float* __restrict__ bb, u16* __restrict__ oh){
  int r = blockIdx.x; int t = threadIdx.x; // 256
  const float* xr = x + (size_t)r*D;
  float v0 = xr[t], v1 = xr[t+256];
  __shared__ float red[256];
  red[t] = v0+v1; __syncthreads();
  for (int st = 128; st > 0; st >>= 1){ if (t < st) red[t] += red[t+st]; __syncthreads(); }
  float mu = red[0]/(float)D;
  __syncthreads();
  float d0 = v0-mu, d1 = v1-mu;
  red[t] = d0*d0 + d1*d1; __syncthreads();
  for (int st = 128; st > 0; st >>= 1){ if (t < st) red[t] += red[t+st]; __syncthreads(); }
  float var = red[0]/(float)D;
  float rs = rsqrtf(var + 1e-5f);
  oh[(size_t)r*D + t]       = f2bf(d0*rs*s[t]       + bb[t]);
  oh[(size_t)r*D + t + 256] = f2bf(d1*rs*s[t+256]   + bb[t+256]);
}

// ---------- self-attn ----------
__launch_bounds__(256)
__global__ void k_selfattn(const float* __restrict__ qkv, u16* __restrict__ oh){
  int bh = blockIdx.x; int b = bh / H, h = bh % H;
  int t = threadIdx.x;
  __shared__ float qs[J*DH], ks[J*DH], vs[J*DH];
  __shared__ float ss[J*J];
  for (int e = t; e < J*DH; e += 256){
    int j = e/DH, d = e%DH;
    const float* base = qkv + (size_t)(b*J+j)*1536 + h*DH + d;
    qs[e] = base[0]; ks[e] = base[512]; vs[e] = base[1024];
  }
  __syncthreads();
  for (int e = t; e < J*J; e += 256){
    int qj = e/J, kk = e%J;
    float acc = 0.f;
    for (int d = 0; d < DH; ++d) acc += qs[qj*DH+d]*ks[kk*DH+d];
    float bias = (qj==kk || c_parent[qj]==kk || c_parent[kk]==qj) ? 0.f : NEGF;
    ss[e] = acc*0.125f + bias;
  }
  __syncthreads();
  if (t < J){
    float m = -3.4e38f;
    for (int k = 0; k < J; ++k) m = fmaxf(m, ss[t*J+k]);
    float sum = 0.f;
    for (int k = 0; k < J; ++k){ float e_ = expf(ss[t*J+k]-m); ss[t*J+k] = e_; sum += e_; }
    float inv = 1.f/sum;
    for (int k = 0; k < J; ++k) ss[t*J+k] *= inv;
  }
  __syncthreads();
  for (int e = t; e < J*DH; e += 256){
    int j = e/DH, d = e%DH;
    float acc = 0.f;
    for (int k = 0; k < J; ++k) acc += ss[j*J+k]*vs[k*DH+d];
    oh[(size_t)(b*J+j)*D + h*DH + d] = f2bf(acc);
  }
}

// ---------- cross-attn over active points ----------
__launch_bounds__(256)
__global__ void k_crossattn(const float* __restrict__ qbuf, const float* __restrict__ kv_act,
                            const float* __restrict__ x_t, const float* __restrict__ pc,
                            const int* __restrict__ act_idx, const int* __restrict__ act_cnt,
                            const int* __restrict__ act_off, const int* __restrict__ rescue,
                            const int* __restrict__ allm, u16* __restrict__ oh){
  int bh = blockIdx.x; int b = bh / H, h = bh % H;
  int t = threadIdx.x;
  int cnt = act_cnt[b], off = act_off[b];
  __shared__ float qs[J*DH];
  __shared__ float ks[CAP*DH];
  __shared__ float pxyz[CAP*3];
  __shared__ float sx[J*3];
  __shared__ int sn[CAP];
  __shared__ float ss[J*CAP];
  if (t < J*3) sx[t] = x_t[b*J*3+t];
  for (int e = t; e < J*DH; e += 256)
    qs[e] = qbuf[(size_t)(b*J + e/DH)*D + h*DH + (e%DH)];
  for (int e = t; e < cnt*DH; e += 256){
    int i = e/DH, d = e%DH;
    ks[e] = kv_act[(size_t)(off+i)*1024 + h*DH + d];
  }
  for (int i = t; i < cnt; i += 256){
    int n = act_idx[b*CAP+i]; sn[i] = n;
    const float* p = pc + ((size_t)b*NP+n)*6;
    pxyz[i*3] = p[0]; pxyz[i*3+1] = p[1]; pxyz[i*3+2] = p[2];
  }
  __syncthreads();
  for (int e = t; e < J*cnt; e += 256){
    int j = e/cnt, i = e%cnt;
    float acc = 0.f;
    for (int d = 0; d < DH; ++d) acc += qs[j*DH+d]*ks[i*DH+d];
    float bias;
    if (allm[b*J+j]) bias = (sn[i] == rescue[b*J+j]) ? 0.f : NEGF;
    else {
      float x0=sx[j*3], x1=sx[j*3+1], x2=sx[j*3+2];
      float p0=pxyz[i*3], p1=pxyz[i*3+1], p2=pxyz[i*3+2];
      float d2 = (x0*x0+x1*x1+x2*x2) + (p0*p0+p1*p1+p2*p2) - 2.f*(x0*p0+x1*p1+x2*p2);
      float dist = sqrtf(fmaxf(d2,0.f));
      float ar = c_scale[j]*0.1f;
      bias = (dist > ar) ? NEGF : 0.f;
    }
    ss[j*CAP+i] = acc*0.125f + bias;
  }
  __syncthreads();
  if (t < J){
    float m = -3.4e38f;
    for (int i = 0; i < cnt; ++i) m = fmaxf(m, ss[t*CAP+i]);
    float sum = 0.f;
    for (int i = 0; i < cnt; ++i){ float e_ = expf(ss[t*CAP+i]-m); ss[t*CAP+i] = e_; sum += e_; }
    float inv = 1.f/sum;
    for (int i = 0; i < cnt; ++i) ss[t*CAP+i] *= inv;
  }
  __syncthreads();
  for (int e = t; e < J*DH; e += 256){
    int j = e/DH, d = e%DH;
    float acc = 0.f;
    for (int i = 0; i < cnt; ++i)
      acc += ss[j*CAP+i]*kv_act[(size_t)(off+i)*1024 + 512 + h*DH + d];
    oh[(size_t)(b*J+j)*D + h*DH + d] = f2bf(acc);
  }
}

// ---------- final vel projection ----------
__global__ void k_vel(const float* __restrict__ x, const float* __restrict__ vel_w,
                      const float* __restrict__ vel_b, float* __restrict__ out){
  int r = blockIdx.x; int t = threadIdx.x; // 192
  int c = t >> 6; int lane = t & 63;
  float acc = 0.f;
  const float* xr = x + (size_t)r*D;
  for (int d = lane; d < D; d += 64) acc += xr[d]*vel_w[d*3+c];
  for (int s = 32; s > 0; s >>= 1) acc += __shfl_down(acc, s);
  if (lane == 0) out[r*3+c] = acc + vel_b[c];
}

// ============================================================================
static GemmArgs mk(const u16* A, const u16* Bt, const float* bias, const float* res,
                   float* Cf, u16* Ch, int M, int N, int K, int act, const int* Mdev, int TM){
  GemmArgs g; g.Ag=A; g.Bt=Bt; g.bias=bias; g.res=res; g.Cf=Cf; g.Ch=Ch;
  g.M=M; g.N=N; g.K=K; g.act=act; g.Mdev=Mdev;
  g.ntx=(M+TM-1)/TM; g.nwg=g.ntx*(N/64); return g;
}

extern "C" void kernel_launch(void* const* d_in, const int* in_sizes, int n_in,
                              void* d_out, int out_size, void* d_ws, size_t ws_size,
                              hipStream_t stream){
  const float* x_t        = (const float*)d_in[0];
  const float* t_in       = (const float*)d_in[1];
  const float* coarse     = (const float*)d_in[2];
  const float* radar      = (const float*)d_in[3];
  const float* pc_w       = (const float*)d_in[4];
  const float* pc_b       = (const float*)d_in[5];
  const float* coarse_w   = (const float*)d_in[6];
  const float* coarse_b   = (const float*)d_in[7];
  const float* state_w    = (const float*)d_in[8];
  const float* state_b    = (const float*)d_in[9];
  const float* jid_emb    = (const float*)d_in[10];
  const float* dop_w1     = (const float*)d_in[11];
  const float* dop_b1     = (const float*)d_in[12];
  const float* dop_w2     = (const float*)d_in[13];
  const float* dop_b2     = (const float*)d_in[14];
  const float* time_w1    = (const float*)d_in[15];
  const float* time_b1    = (const float*)d_in[16];
  const float* time_w2    = (const float*)d_in[17];
  const float* time_b2    = (const float*)d_in[18];
  const float* mod_w1     = (const float*)d_in[19];
  const float* mod_b1     = (const float*)d_in[20];
  const float* mod_w2     = (const float*)d_in[21];
  const float* mod_b2     = (const float*)d_in[22];
  const float* diff_w     = (const float*)d_in[23];
  const float* diff_b     = (const float*)d_in[24];
  const float* vel_w      = (const float*)d_in[25];
  const float* vel_b      = (const float*)d_in[26];
  const float* sa_qkv_w   = (const float*)d_in[27];
  const float* sa_qkv_b   = (const float*)d_in[28];
  const float* sa_out_w   = (const float*)d_in[29];
  const float* sa_out_b   = (const float*)d_in[30];
  const float* ca_qkv_w   = (const float*)d_in[31];
  const float* ca_qkv_b   = (const float*)d_in[32];
  const float* ca_out_w   = (const float*)d_in[33];
  const float* ca_out_b   = (const float*)d_in[34];
  const float* ff1_w      = (const float*)d_in[35];
  const float* ff1_b      = (const float*)d_in[36];
  const float* ff2_w      = (const float*)d_in[37];
  const float* ff2_b      = (const float*)d_in[38];
  const float* ln1_s      = (const float*)d_in[39];
  const float* ln1_b      = (const float*)d_in[40];
  const float* ln2_s      = (const float*)d_in[41];
  const float* ln2_b      = (const float*)d_in[42];
  const float* ln3_s      = (const float*)d_in[43];
  const float* ln3_b      = (const float*)d_in[44];
  (void)in_sizes; (void)n_in; (void)out_size; (void)ws_size;

  const int R = NB*J; // 1728

  char* wp = (char*)d_ws;
  auto alloc = [&](size_t bytes)->void*{
    void* r = (void*)wp;
    wp += (bytes + 255) & ~(size_t)255;
    return r;
  };
  float*        denom_sum = (float*)alloc(R*4);
  int*          rescue    = (int*)  alloc(R*4);
  int*          allm      = (int*)  alloc(R*4);
  unsigned int* bitmap    = (unsigned int*)alloc(NB*(NP/32)*4);
  int*          act_idx   = (int*)  alloc(NB*CAP*4);
  int*          act_cnt   = (int*)  alloc(NB*4);
  int*          act_off   = (int*)  alloc(NB*4);
  int*          act_total = (int*)  alloc(64);
  float* Gp       = (float*)alloc((size_t)NB*GCH*J*64*4);
  float* h_dop    = (float*)alloc((size_t)R*D*4);
  float* h_state  = (float*)alloc((size_t)R*D*4);
  float* h_coarse = (float*)alloc((size_t)R*D*4);
  float* hstruct  = (float*)alloc((size_t)R*D*4);
  float* xres     = (float*)alloc((size_t)R*D*4);
  float* qbuf     = (float*)alloc((size_t)R*D*4);
  float* h_time   = (float*)alloc((size_t)NB*D*4);
  float* mod2     = (float*)alloc((size_t)R*2*D*4);
  float* qkv      = (float*)alloc((size_t)R*3*D*4);
  float* kv_act   = (float*)alloc((size_t)NB*CAP*2*D*4);   // stage-1 aliases hs2
  u16* hsh   = (u16*)alloc((size_t)R*D*2);
  u16* hbufh = (u16*)alloc((size_t)R*D*2);
  u16* attnoh= (u16*)alloc((size_t)R*D*2);
  u16* ffhh  = (u16*)alloc((size_t)R*DFF*2);
  u16* mah   = (u16*)alloc((size_t)NB*CAP*D*2);
  u16* time_w2t = (u16*)alloc((size_t)512*512*2);
  u16* mod_w1t  = (u16*)alloc((size_t)1024*512*2);
  u16* mod_w2t  = (u16*)alloc((size_t)1024*1024*2);
  u16* diff_wt  = (u16*)alloc((size_t)512*1024*2);
  u16* sa_qkv_t = (u16*)alloc((size_t)NLAYER*1536*512*2);
  u16* sa_out_t = (u16*)alloc((size_t)NLAYER*512*512*2);
  u16* ca_qkv_t = (u16*)alloc((size_t)NLAYER*1536*512*2);
  u16* ca_out_t = (u16*)alloc((size_t)NLAYER*512*512*2);
  u16* ff1_t    = (u16*)alloc((size_t)NLAYER*2048*512*2);
  u16* ff2_t    = (u16*)alloc((size_t)NLAYER*512*2048*2);
  // stage-1-only aliases
  u16* thh   = attnoh;
  u16* mod1h = ffhh;
  u16* hs2h  = (u16*)kv_act;

  // ---- single-launch weight conversion ----
  {
    WcTab tab;
    int s = 0;
    auto set = [&](int i, const float* src, u16* dst, int K, int N, int L){
      tab.d[i].src = src; tab.d[i].dst = dst; tab.d[i].K = K; tab.d[i].N = N;
      tab.d[i].tk = K/64; tab.d[i].tn = N/64; tab.d[i].L = L; tab.d[i].start = s;
      s += (K/64)*(N/64)*L;
    };
    set(0, time_w2, time_w2t, 512, 512, 1);
    set(1, mod_w1,  mod_w1t,  512, 1024, 1);
    set(2, mod_w2,  mod_w2t,  1024, 1024, 1);
    set(3, diff_w,  diff_wt,  1024, 512, 1);
    set(4, sa_qkv_w, sa_qkv_t, 512, 1536, NLAYER);
    set(5, sa_out_w, sa_out_t, 512, 512, NLAYER);
    set(6, ca_qkv_w, ca_qkv_t, 512, 1536, NLAYER);
    set(7, ca_out_w, ca_out_t, 512, 512, NLAYER);
    set(8, ff1_w,    ff1_t,    512, 2048, NLAYER);
    set(9, ff2_w,    ff2_t,    2048, 512, NLAYER);
    k_wconv_all<<<s, 256, 0, stream>>>(tab);
  }

  // ---- stage 0 ----
  hipMemsetAsync(bitmap, 0, NB*(NP/32)*4, stream);
  k_perj<<<R, 256, 0, stream>>>(x_t, radar, denom_sum, rescue, allm, bitmap);
  k_compact<<<NB, 64, 0, stream>>>(bitmap, act_idx, act_cnt);
  k_scan<<<1, 64, 0, stream>>>(act_cnt, act_off, act_total);
  k_gpart<<<dim3(NB, GCH), 256, 0, stream>>>(x_t, radar, dop_w1, dop_b1, Gp);
  k_hdop2<<<dim3(NB, 2), 256, 0, stream>>>(Gp, dop_w2, dop_b2, denom_sum, h_dop);

  // ---- stage 1 ----
  k_stage1<<<(2*R*D + NB*D + 255)/256, 256, 0, stream>>>(
      x_t, state_w, state_b, coarse, coarse_w, coarse_b, t_in, time_w1, time_b1,
      h_state, hsh, h_coarse, thh);
  { GemmArgs g = mk(thh, time_w2t, time_b2, nullptr, h_time, nullptr, NB, 512, 512, 0, nullptr, 32);
    k_gemm<32><<<g.nwg, 256, 0, stream>>>(g); }
  { GemmArgs g = mk(hsh, mod_w1t, mod_b1, nullptr, nullptr, mod1h, R, 1024, 512, 1, nullptr, 32);
    k_gemm<32><<<g.nwg, 256, 0, stream>>>(g); }
  { GemmArgs g = mk(mod1h, mod_w2t, mod_b2, nullptr, mod2, nullptr, R, 1024, 1024, 0, nullptr, 32);
    k_gemm<32><<<g.nwg, 256, 0, stream>>>(g); }
  k_hs2<<<(R*2*D+255)/256, 256, 0, stream>>>(h_state, hs2h);
  { GemmArgs g = mk(hs2h, diff_wt, diff_b, nullptr, hstruct, nullptr, R, 512, 1024, 0, nullptr, 32);
    k_gemm<32><<<g.nwg, 256, 0, stream>>>(g); }
  k_query<<<(R*D+255)/256, 256, 0, stream>>>(h_coarse, h_time, h_dop, h_state, hstruct,
                                             jid_emb, mod2, xres);
  k_memact<<<NB*CAP, 128, 0, stream>>>(x_t, radar, pc_w, pc_b, act_idx, act_cnt, act_off, mah);

  // ---- stage 2: transformer layers ----
  for (int l = 0; l < NLAYER; ++l){
    k_ln<<<R, 256, 0, stream>>>(xres, ln1_s + l*D, ln1_b + l*D, hbufh);
    { GemmArgs g = mk(hbufh, sa_qkv_t + (size_t)l*1536*512, sa_qkv_b + l*1536, nullptr,
                      qkv, nullptr, R, 1536, 512, 0, nullptr, 64);
      k_gemm<64><<<g.nwg, 256, 0, stream>>>(g); }
    k_selfattn<<<NB*H, 256, 0, stream>>>(qkv, attnoh);
    { GemmArgs g = mk(attnoh, sa_out_t + (size_t)l*512*512, sa_out_b + l*D, xres,
                      xres, nullptr, R, 512, 512, 0, nullptr, 32);
      k_gemm<32><<<g.nwg, 256, 0, stream>>>(g); }

    k_ln<<<R, 256, 0, stream>>>(xres, ln2_s + l*D, ln2_b + l*D, hbufh);
    { GemmArgs ga = mk(hbufh, ca_qkv_t + (size_t)l*1536*512, ca_qkv_b + l*1536, nullptr,
                       qbuf, nullptr, R, 512, 512, 0, nullptr, 32);
      GemmArgs gb = mk(mah, ca_qkv_t + (size_t)l*1536*512 + (size_t)512*512,
                       ca_qkv_b + l*1536 + 512, nullptr,
                       kv_act, nullptr, NB*CAP, 1024, 512, 0, act_total, 64);
      k_gemm_dual<<<ga.nwg + gb.nwg, 256, 0, stream>>>(ga, gb); }
    k_crossattn<<<NB*H, 256, 0, stream>>>(qbuf, kv_act, x_t, radar, act_idx, act_cnt,
                                          act_off, rescue, allm, attnoh);
    { GemmArgs g = mk(attnoh, ca_out_t + (size_t)l*512*512, ca_out_b + l*D, xres,
                      xres, nullptr, R, 512, 512, 0, nullptr, 32);
      k_gemm<32><<<g.nwg, 256, 0, stream>>>(g); }

    k_ln<<<R, 256, 0, stream>>>(xres, ln3_s + l*D, ln3_b + l*D, hbufh);
    { GemmArgs g = mk(hbufh, ff1_t + (size_t)l*2048*512, ff1_b + l*DFF, nullptr,
                      nullptr, ffhh, R, 2048, 512, 2, nullptr, 64);
      k_gemm<64><<<g.nwg, 256, 0, stream>>>(g); }
    { GemmArgs g = mk(ffhh, ff2_t + (size_t)l*512*2048, ff2_b + l*D, xres,
                      xres, nullptr, R, 512, 2048, 0, nullptr, 32);
      k_gemm<32><<<g.nwg, 256, 0, stream>>>(g); }
  }

  k_vel<<<R, 192, 0, stream>>>(xres, vel_w, vel_b, (float*)d_out);
}

// Round 8
// 1000.851 us; speedup vs baseline: 1.2554x; 1.2554x over previous
//
#include <hip/hip_runtime.h>

#define J 27
#define D 512
#define H 8
#define DH 64
#define NLAYER 6
#define DFF 2048
#define NB 64
#define NP 2048
#define CAP 128
#define GCH 16
#define GPTS 128
#define NEGF -1000000000.0f

typedef unsigned short u16;
typedef __attribute__((ext_vector_type(8))) __bf16 bf16x8;
typedef __attribute__((ext_vector_type(4))) float f32x4;

__constant__ int c_parent[J] = {0,0,1,2,3,4,5,6,7,8,8,3,11,12,13,14,15,15,0,18,19,20,0,22,23,24,3};
__constant__ float c_scale[J] = {0.6f,0.6f,0.6f,0.6f,1.f,1.f,1.f,1.f,1.f,1.5f,1.5f,1.f,1.f,1.f,1.f,1.f,
                                 1.5f,1.5f,0.6f,1.f,1.5f,1.5f,0.6f,1.f,1.5f,1.5f,1.5f};

__device__ __forceinline__ float siluf(float x){ return x/(1.f+expf(-x)); }

__device__ __forceinline__ u16 f2bf(float f){
  union { float f; unsigned u; } x; x.f = f;
  unsigned r = x.u + 0x7FFFu + ((x.u >> 16) & 1u);
  return (u16)(r >> 16);
}

// ---------- per (b,j): denom sum, rescue idx, allmask, active-bitmap marks ----------
__global__ void k_perj(const float* __restrict__ x_t, const float* __restrict__ pc,
                       float* __restrict__ denom_sum, int* __restrict__ rescue,
                       int* __restrict__ allm, unsigned int* __restrict__ bitmap){
  int bj = blockIdx.x; int b = bj / J, j = bj % J;
  int t = threadIdx.x;
  float x0 = x_t[(b*J+j)*3+0];
  float x1 = x_t[(b*J+j)*3+1];
  float x2 = x_t[(b*J+j)*3+2];
  float sx = x0*x0+x1*x1+x2*x2;
  float ar = c_scale[j]*0.1f;
  float sig = ar*0.5f;
  float twos2 = 2.f*sig*sig;
  float sum = 0.f, bmin = 3.4e38f; int bidx = NP; int any = 0;
  for (int n = t; n < NP; n += 256){
    const float* p = pc + ((size_t)b*NP + n)*6;
    float p0=p[0], p1=p[1], p2=p[2];
    float d2 = sx + (p0*p0+p1*p1+p2*p2) - 2.f*(x0*p0+x1*p1+x2*p2);
    float dist = sqrtf(fmaxf(d2, 0.f));
    sum += expf(-(dist*dist)/twos2);
    if (dist < bmin){ bmin = dist; bidx = n; }
    if (dist <= ar){ any = 1; atomicOr(&bitmap[b*(NP/32)+(n>>5)], 1u<<(n&31)); }
  }
  __shared__ float ssum[256]; __shared__ float smin[256];
  __shared__ int sidx[256]; __shared__ int sany[256];
  ssum[t]=sum; smin[t]=bmin; sidx[t]=bidx; sany[t]=any;
  __syncthreads();
  for (int s = 128; s > 0; s >>= 1){
    if (t < s){
      ssum[t] += ssum[t+s];
      if (smin[t+s] < smin[t] || (smin[t+s]==smin[t] && sidx[t+s] < sidx[t])){ smin[t]=smin[t+s]; sidx[t]=sidx[t+s]; }
      sany[t] |= sany[t+s];
    }
    __syncthreads();
  }
  if (t == 0){
    denom_sum[bj] = ssum[0];
    rescue[bj] = sidx[0];
    allm[bj] = sany[0] ? 0 : 1;
    if (!sany[0]) atomicOr(&bitmap[b*(NP/32)+(sidx[0]>>5)], 1u<<(sidx[0]&31));
  }
}

// ---------- compaction + scan fused (single block, 16 waves) ----------
__global__ void k_compact(const unsigned int* __restrict__ bitmap, int* __restrict__ act_idx,
                          int* __restrict__ act_cnt, int* __restrict__ act_off,
                          int* __restrict__ act_total){
  int t = threadIdx.x;              // 1024
  int wv = t >> 6, lane = t & 63;
  for (int b = wv; b < NB; b += 16){
    unsigned int w = bitmap[b*(NP/32)+lane];
    int c = __popc(w);
    int off = c;
    for (int s = 1; s < 64; s <<= 1){
      int v = __shfl_up(off, s);
      if (lane >= s) off += v;
    }
    int total = __shfl(off, 63);
    off -= c;
    int base = off;
    for (int bit = 0; bit < 32; ++bit){
      if (w & (1u<<bit)){
        if (base < CAP) act_idx[b*CAP+base] = lane*32+bit;
        base++;
      }
    }
    if (lane == 0) act_cnt[b] = total > CAP ? CAP : total;
  }
  __syncthreads();
  if (t == 0){
    int s = 0;
    for (int b = 0; b < NB; ++b){ act_off[b] = s; s += act_cnt[b]; }
    act_total[0] = s;
  }
}

// ---------- G[b,ch,j,h] = sum_p dws[b,j,p] * silu(dop*w1[h]+b1[h])  via MFMA ----------
__launch_bounds__(256)
__global__ void k_gpart(const float* __restrict__ x_t, const float* __restrict__ pc,
                        const float* __restrict__ dop_w1, const float* __restrict__ dop_b1,
                        float* __restrict__ Gp){
  int b = blockIdx.x, ch = blockIdx.y; int t = threadIdx.x;
  __shared__ float sx[J*3];
  __shared__ float w1s[64], b1s[64];
  __shared__ float spx[GPTS], spy[GPTS], spz[GPTS], sdp[GPTS];
  __shared__ u16 hidT[64*128];
  __shared__ u16 dwsA[32*128];
  if (t < J*3) sx[t] = x_t[b*J*3 + t];
  if (t < 64){ w1s[t] = dop_w1[t]; b1s[t] = dop_b1[t]; }
  int n0 = ch*GPTS;
  if (t < GPTS){
    const float* p = pc + ((size_t)b*NP + n0 + t)*6;
    float2 f0 = *(const float2*)p;
    float2 f1 = *(const float2*)(p+2);
    spx[t]=f0.x; spy[t]=f0.y; spz[t]=f1.x; sdp[t]=f1.y;
  }
  __syncthreads();
  {
    int h = t & 63, pb = (t>>6)*32;
    float w1 = w1s[h], b1 = b1s[h];
    char* base = (char*)hidT;
    #pragma unroll
    for (int m = 0; m < 16; ++m){
      float v0 = siluf(sdp[pb+2*m]*w1 + b1);
      float v1 = siluf(sdp[pb+2*m+1]*w1 + b1);
      unsigned pk = (unsigned)f2bf(v0) | ((unsigned)f2bf(v1) << 16);
      int off = (h*256 + pb*2 + 4*m) ^ ((h&7)<<4);
      *(unsigned*)(base + off) = pk;
    }
  }
  {
    int j = t & 31, pb = (t>>5)*16;
    if (j < J){
      float x0=sx[j*3], x1=sx[j*3+1], x2=sx[j*3+2];
      float sxx = x0*x0+x1*x1+x2*x2;
      float sig = c_scale[j]*0.05f;
      float inv2 = 1.f/(2.f*sig*sig);
      char* base = (char*)dwsA;
      #pragma unroll
      for (int m = 0; m < 8; ++m){
        float v[2];
        #pragma unroll
        for (int u = 0; u < 2; ++u){
          int p = pb + 2*m + u;
          float p0=spx[p], p1=spy[p], p2=spz[p];
          float d2 = sxx + (p0*p0+p1*p1+p2*p2) - 2.f*(x0*p0+x1*p1+x2*p2);
          float dist = sqrtf(fmaxf(d2, 0.f));
          v[u] = expf(-(dist*dist)*inv2);
        }
        unsigned pk = (unsigned)f2bf(v[0]) | ((unsigned)f2bf(v[1]) << 16);
        int off = (j*256 + pb*2 + 4*m) ^ ((j&7)<<4);
        *(unsigned*)(base + off) = pk;
      }
    }
  }
  __syncthreads();
  int lane = t & 63, wv = t >> 6;
  int h0 = wv * 16;
  int fr = lane & 15, fkb = (lane>>4)*16;
  f32x4 acc[2] = {};
  #pragma unroll
  for (int ks = 0; ks < 4; ++ks){
    bf16x8 bfrag;
    {
      int row = h0 + fr;
      int adr = (row*256 + ks*64 + fkb) ^ ((row&7)<<4);
      bfrag = *(const bf16x8*)((char*)hidT + adr);
    }
    #pragma unroll
    for (int m = 0; m < 2; ++m){
      int row = m*16 + fr;
      int adr = (row*256 + ks*64 + fkb) ^ ((row&7)<<4);
      bf16x8 afrag = *(const bf16x8*)((char*)dwsA + adr);
      acc[m] = __builtin_amdgcn_mfma_f32_16x16x32_bf16(afrag, bfrag, acc[m], 0,0,0);
    }
  }
  float* out = Gp + ((size_t)(b*GCH+ch))*J*64;
  int er = (lane>>4)*4, ec = lane&15;
  #pragma unroll
  for (int m = 0; m < 2; ++m){
    #pragma unroll
    for (int q = 0; q < 4; ++q){
      int j = m*16 + er + q;
      if (j < J) out[j*64 + h0 + ec] = acc[m][q];
    }
  }
}

// ---------- h_dop: chunk-reduce Gp inline; one block per (b, d-half) ----------
__launch_bounds__(256)
__global__ void k_hdop2(const float* __restrict__ Gp, const float* __restrict__ dop_w2,
                        const float* __restrict__ dop_b2, const float* __restrict__ denom_sum,
                        float* __restrict__ h_dop){
  int b = blockIdx.x, half = blockIdx.y;
  int t = threadIdx.x;
  int d = half*256 + t;
  __shared__ float sG[J*64];
  __shared__ float sS[J], sI[J];
  for (int e = t; e < J*64; e += 256){
    float s = 0.f;
    #pragma unroll
    for (int c = 0; c < GCH; ++c) s += Gp[(size_t)(b*GCH+c)*J*64 + e];
    sG[e] = s;
  }
  if (t < J){ float S = denom_sum[b*J+t]; sS[t] = S; sI[t] = 1.f/(S+1e-6f); }
  __syncthreads();
  float acc[J];
  #pragma unroll
  for (int j = 0; j < J; ++j) acc[j] = 0.f;
  for (int h = 0; h < 64; ++h){
    float wv = dop_w2[h*D + d];
    #pragma unroll
    for (int j = 0; j < J; ++j) acc[j] += sG[j*64+h]*wv;
  }
  float b2 = dop_b2[d];
  #pragma unroll
  for (int j = 0; j < J; ++j)
    h_dop[(size_t)(b*J+j)*D + d] = (acc[j] + sS[j]*b2)*sI[j];
}

// ---------- merged stage-1 elementwise: h_state(+bf16), h_coarse, th(bf16), hs2(bf16) ----------
__global__ void k_stage1(const float* __restrict__ x_t, const float* __restrict__ state_w,
                         const float* __restrict__ state_b,
                         const float* __restrict__ coarse, const float* __restrict__ coarse_w,
                         const float* __restrict__ coarse_b,
                         const float* __restrict__ t_in, const float* __restrict__ time_w1,
                         const float* __restrict__ time_b1,
                         float* __restrict__ h_state, u16* __restrict__ hsh,
                         float* __restrict__ h_coarse, u16* __restrict__ thh,
                         u16* __restrict__ hs2h){
  const int RD = NB*J*D;
  int idx = blockIdx.x*256 + threadIdx.x;
  if (idx < RD){
    int r = idx / D, d = idx % D;
    const float* ir = x_t + r*3;
    float v = ir[0]*state_w[d] + ir[1]*state_w[D+d] + ir[2]*state_w[2*D+d] + state_b[d];
    h_state[idx] = v;
    hsh[idx] = f2bf(v);
  } else if (idx < 2*RD){
    int k = idx - RD;
    int r = k / D, d = k % D;
    const float* ir = coarse + r*3;
    h_coarse[k] = ir[0]*coarse_w[d] + ir[1]*coarse_w[D+d] + ir[2]*coarse_w[2*D+d] + coarse_b[d];
  } else if (idx < 2*RD + NB*D){
    int k = idx - 2*RD;
    int b = k / D, d = k % D;
    float v = siluf(t_in[b]*time_w1[d] + time_b1[d]);
    thh[k] = f2bf(v);
  } else if (idx < 4*RD + NB*D){
    int k = idx - (2*RD + NB*D);
    int r = k / (2*D), c = k % (2*D);
    int b = r / J, j = r % J;
    int src = (c < D) ? r : (b*J + c_parent[j]);
    int d = (c < D) ? c : c - D;
    const float* ir = x_t + src*3;
    float v = ir[0]*state_w[d] + ir[1]*state_w[D+d] + ir[2]*state_w[2*D+d] + state_b[d];
    hs2h[k] = f2bf(v);
  }
}

__global__ void k_query(const float* __restrict__ h_coarse, const float* __restrict__ h_time,
                        const float* __restrict__ h_dop, const float* __restrict__ h_state,
                        const float* __restrict__ hstruct, const float* __restrict__ jid,
                        const float* __restrict__ mod2, float* __restrict__ x){
  int idx = blockIdx.x*256 + threadIdx.x;
  if (idx >= NB*J*D) return;
  int r = idx / D, d = idx % D;
  int b = r / J, j = r % J;
  float q = h_coarse[idx] + h_time[b*D+d] + h_dop[idx] + h_state[idx] + hstruct[idx] + jid[j*D+d];
  float shift = mod2[(size_t)r*2*D + d];
  float scale = mod2[(size_t)r*2*D + D + d];
  x[idx] = q*(1.f+scale) + shift;
}

// ---------- memory rows for active points (bf16) ----------
__global__ void k_memact(const float* __restrict__ x_t, const float* __restrict__ pc,
                         const float* __restrict__ pc_w, const float* __restrict__ pc_b,
                         const int* __restrict__ act_idx, const int* __restrict__ act_cnt,
                         const int* __restrict__ act_off, u16* __restrict__ mh){
  int b = blockIdx.x / CAP, i = blockIdx.x % CAP;
  if (i >= act_cnt[b]) return;
  int n = act_idx[b*CAP+i];
  int t = threadIdx.x; // 128
  __shared__ float sdw[J];
  __shared__ float spi;
  const float* p = pc + ((size_t)b*NP+n)*6;
  if (t < J){
    float x0 = x_t[(b*J+t)*3+0], x1 = x_t[(b*J+t)*3+1], x2 = x_t[(b*J+t)*3+2];
    float p0=p[0], p1=p[1], p2=p[2];
    float d2 = (x0*x0+x1*x1+x2*x2) + (p0*p0+p1*p1+p2*p2) - 2.f*(x0*p0+x1*p1+x2*p2);
    float dist = sqrtf(fmaxf(d2,0.f));
    float sig = c_scale[t]*0.05f;
    sdw[t] = expf(-(dist*dist)/(2.f*sig*sig));
  }
  __syncthreads();
  if (t == 0){ float m = sdw[0]; for (int k = 1; k < J; ++k) m = fmaxf(m, sdw[k]); spi = m; }
  __syncthreads();
  float pi = spi;
  float p0=p[0],p1=p[1],p2=p[2],p3=p[3],p4=p[4],p5=p[5];
  int g = act_off[b] + i;
  for (int d = t; d < D; d += 128){
    float acc = pc_b[d] + p0*pc_w[d] + p1*pc_w[D+d] + p2*pc_w[2*D+d]
              + p3*pc_w[3*D+d] + p4*pc_w[4*D+d] + p5*pc_w[5*D+d];
    mh[(size_t)g*D + d] = f2bf(acc * pi);
  }
}

// ---------- single-launch weight conversion (vectorized) ----------
struct WcD { const float* src; u16* dst; int K; int N; int tk; int tn; int L; int start; };
struct WcTab { WcD d[10]; };
__launch_bounds__(256)
__global__ void k_wconv_all(WcTab tab){
  int tid = blockIdx.x;
  WcD w = tab.d[0];
  #pragma unroll
  for (int i = 0; i < 10; ++i){
    int end = tab.d[i].start + tab.d[i].tk*tab.d[i].tn*tab.d[i].L;
    if (tid >= tab.d[i].start && tid < end) w = tab.d[i];
  }
  int local = tid - w.start;
  int per = w.tk*w.tn;
  int l = local / per, rem = local % per;
  int k0 = (rem % w.tk)*64, n0 = (rem / w.tk)*64;
  size_t zo = (size_t)l*w.K*w.N;
  __shared__ float tile[64][65];
  int t = threadIdx.x;
  #pragma unroll
  for (int i = 0; i < 4; ++i){
    int lin = i*256 + t;          // 0..1023
    int k = lin >> 4, nc = lin & 15;
    float4 v = *(const float4*)&w.src[zo + (size_t)(k0+k)*w.N + n0 + nc*4];
    tile[k][nc*4+0]=v.x; tile[k][nc*4+1]=v.y; tile[k][nc*4+2]=v.z; tile[k][nc*4+3]=v.w;
  }
  __syncthreads();
  #pragma unroll
  for (int i = 0; i < 2; ++i){
    int lin = i*256 + t;          // 0..511
    int n = lin >> 3, kc = lin & 7;
    unsigned pk[4];
    #pragma unroll
    for (int u = 0; u < 4; ++u)
      pk[u] = (unsigned)f2bf(tile[kc*8+2*u][n]) | ((unsigned)f2bf(tile[kc*8+2*u+1][n])<<16);
    *(uint4*)&w.dst[zo + (size_t)(n0+n)*w.K + k0 + kc*8] = make_uint4(pk[0],pk[1],pk[2],pk[3]);
  }
}

// ---------- MFMA GEMM core (single-buffered, round-6 structure) ----------
struct GemmArgs {
  const u16* Ag; const u16* Bt; const float* bias; const float* res;
  float* Cf; u16* Ch; int M, N, K, act; const int* Mdev; int ntx; int nwg;
};

template<int TM>
__device__ __forceinline__ void gemm_body(const GemmArgs g, int bid, char* smem){
  int Meff = g.Mdev ? *g.Mdev : g.M;
  int q8 = g.nwg>>3, r8 = g.nwg&7;
  int xcd = bid&7, loc = bid>>3;
  int wg = (xcd < r8 ? xcd*(q8+1) : r8*(q8+1)+(xcd-r8)*q8) + loc;
  int row0 = (wg % g.ntx)*TM, col0 = (wg / g.ntx)*64;
  if (row0 >= Meff) return;
  char* sA = smem;
  char* sB = smem + TM*64*2;
  int t = threadIdx.x;
  int lane = t&63, w = t>>6, wr = w>>1, wc = w&1;
  int sm = t>>3, kc = t&7;
  int K = g.K, N = g.N;
  const u16* pA1 = g.Ag + (size_t)(row0+sm)*K + kc*8;
  const u16* pA2 = (TM==64) ? g.Ag + (size_t)(row0+sm+32)*K + kc*8 : pA1;
  const u16* pB1 = g.Bt + (size_t)(col0+sm)*K + kc*8;
  const u16* pB2 = g.Bt + (size_t)(col0+sm+32)*K + kc*8;
  int o1 = (sm*128 + kc*16) ^ ((sm&7)<<4);
  int o2 = ((sm+32)*128 + kc*16) ^ ((sm&7)<<4);
  uint4 ra1, ra2, rb1, rb2;
  auto gload = [&](int kt){
    ra1 = *(const uint4*)(pA1 + kt);
    if constexpr (TM==64) ra2 = *(const uint4*)(pA2 + kt);
    rb1 = *(const uint4*)(pB1 + kt);
    rb2 = *(const uint4*)(pB2 + kt);
  };
  auto stage = [&](){
    *(uint4*)(sA + o1) = ra1;
    if constexpr (TM==64) *(uint4*)(sA + o2) = ra2;
    *(uint4*)(sB + o1) = rb1;
    *(uint4*)(sB + o2) = rb2;
  };
  constexpr int MFR = TM/32;
  constexpr int RW  = TM/2;
  int fr = lane&15, fkb = (lane>>4)*16;
  f32x4 acc[MFR][2] = {};
  gload(0);
  stage();
  __syncthreads();
  for (int kt = 0; kt < K; kt += 64){
    bool nxt = kt + 64 < K;
    if (nxt) gload(kt + 64);
    #pragma unroll
    for (int kk = 0; kk < 2; ++kk){
      bf16x8 af[MFR], bf[2];
      #pragma unroll
      for (int m = 0; m < MFR; ++m){
        int row = wr*RW + m*16 + fr;
        int adr = (row*128 + kk*64 + fkb) ^ ((row&7)<<4);
        af[m] = *(const bf16x8*)(sA + adr);
      }
      #pragma unroll
      for (int n = 0; n < 2; ++n){
        int rowb = wc*32 + n*16 + fr;
        int adr = (rowb*128 + kk*64 + fkb) ^ ((rowb&7)<<4);
        bf[n] = *(const bf16x8*)(sB + adr);
      }
      #pragma unroll
      for (int m = 0; m < MFR; ++m)
        #pragma unroll
        for (int n = 0; n < 2; ++n)
          acc[m][n] = __builtin_amdgcn_mfma_f32_16x16x32_bf16(af[m], bf[n], acc[m][n], 0,0,0);
    }
    if (nxt){
      __syncthreads();
      stage();
      __syncthreads();
    }
  }
  int er = (lane>>4)*4, ec = lane&15;
  #pragma unroll
  for (int m = 0; m < MFR; ++m){
    #pragma unroll
    for (int qq = 0; qq < 4; ++qq){
      int r = row0 + wr*RW + m*16 + er + qq;
      if (r >= Meff) continue;
      #pragma unroll
      for (int n = 0; n < 2; ++n){
        int c = col0 + wc*32 + n*16 + ec;
        float v = acc[m][n][qq] + g.bias[c];
        if (g.res) v += g.res[(size_t)r*N + c];
        if (g.act == 1) v = v/(1.f+expf(-v));
        else if (g.act == 2) v = fmaxf(v, 0.f);
        if (g.Cf) g.Cf[(size_t)r*N + c] = v;
        if (g.Ch) g.Ch[(size_t)r*N + c] = f2bf(v);
      }
    }
  }
}

template<int TM>
__launch_bounds__(256)
__global__ void k_gemm(GemmArgs g){
  __shared__ __align__(16) char smem[TM*64*2 + 64*64*2];
  gemm_body<TM>(g, blockIdx.x, smem);
}

template<int TMA, int TMB>
__launch_bounds__(256)
__global__ void k_gemm_dual(GemmArgs ga, GemmArgs gb){
  constexpr int SA = TMA*64*2 + 64*64*2;
  constexpr int SB = TMB*64*2 + 64*64*2;
  constexpr int SZ = SA > SB ? SA : SB;
  __shared__ __align__(16) char smem[SZ];
  if ((int)blockIdx.x < ga.nwg) gemm_body<TMA>(ga, blockIdx.x, smem);
  else                          gemm_body<TMB>(gb, blockIdx.x - ga.nwg, smem);
}

// ---------- LayerNorm over D, per row -> bf16 ----------
__global__ void k_ln(const float* __restrict__ x, const float* __restrict__ s,
                     const float* __restrict__ bb, u16* __restrict__ oh){
  int r = blockIdx.x; int t = threadIdx.x; // 256
  const float* xr = x + (size_t)r*D;
  float v0 = xr[t], v1 = xr[t+256];
  __shared__ float red[256];
  red[t] = v0+v1; __syncthreads();
  for (int st = 128; st > 0; st >>= 1){ if (t < st) red[t] += red[t+st]; __syncthreads(); }
  float mu = red[0]/(float)D;
  __syncthreads();
  float d0 = v0-mu, d1 = v1-mu;
  red[t] = d0*d0 + d1*d1; __syncthreads();
  for (int st = 128; st > 0; st >>= 1){ if (t < st) red[t] += red[t+st]; __syncthreads(); }
  float var = red[0]/(float)D;
  float rs = rsqrtf(var + 1e-5f);
  oh[(size_t)r*D + t]       = f2bf(d0*rs*s[t]       + bb[t]);
  oh[(size_t)r*D + t + 256] = f2bf(d1*rs*s[t+256]   + bb[t+256]);
}

// ---------- self-attn ----------
__launch_bounds__(256)
__global__ void k_selfattn(const float* __restrict__ qkv, u16* __restrict__ oh){
  int bh = blockIdx.x; int b = bh / H, h = bh % H;
  int t = threadIdx.x;
  __shared__ float qs[J*DH], ks[J*DH], vs[J*DH];
  __shared__ float ss[J*J];
  for (int e = t; e < J*DH; e += 256){
    int j = e/DH, d = e%DH;
    const float* base = qkv + (size_t)(b*J+j)*1536 + h*DH + d;
    qs[e] = base[0]; ks[e] = base[512]; vs[e] = base[1024];
  }
  __syncthreads();
  for (int e = t; e < J*J; e += 256){
    int qj = e/J, kk = e%J;
    float acc = 0.f;
    for (int d = 0; d < DH; ++d) acc += qs[qj*DH+d]*ks[kk*DH+d];
    float bias = (qj==kk || c_parent[qj]==kk || c_parent[kk]==qj) ? 0.f : NEGF;
    ss[e] = acc*0.125f + bias;
  }
  __syncthreads();
  if (t < J){
    float m = -3.4e38f;
    for (int k = 0; k < J; ++k) m = fmaxf(m, ss[t*J+k]);
    float sum = 0.f;
    for (int k = 0; k < J; ++k){ float e_ = expf(ss[t*J+k]-m); ss[t*J+k] = e_; sum += e_; }
    float inv = 1.f/sum;
    for (int k = 0; k < J; ++k) ss[t*J+k] *= inv;
  }
  __syncthreads();
  for (int e = t; e < J*DH; e += 256){
    int j = e/DH, d = e%DH;
    float acc = 0.f;
    for (int k = 0; k < J; ++k) acc += ss[j*J+k]*vs[k*DH+d];
    oh[(size_t)(b*J+j)*D + h*DH + d] = f2bf(acc);
  }
}

// ---------- cross-attn over active points ----------
__launch_bounds__(256)
__global__ void k_crossattn(const float* __restrict__ qbuf, const float* __restrict__ kv_act,
                            const float* __restrict__ x_t, const float* __restrict__ pc,
                            const int* __restrict__ act_idx, const int* __restrict__ act_cnt,
                            const int* __restrict__ act_off, const int* __restrict__ rescue,
                            const int* __restrict__ allm, u16* __restrict__ oh){
  int bh = blockIdx.x; int b = bh / H, h = bh % H;
  int t = threadIdx.x;
  int cnt = act_cnt[b], off = act_off[b];
  __shared__ float qs[J*DH];
  __shared__ float ks[CAP*DH];
  __shared__ float pxyz[CAP*3];
  __shared__ float sx[J*3];
  __shared__ int sn[CAP];
  __shared__ float ss[J*CAP];
  if (t < J*3) sx[t] = x_t[b*J*3+t];
  for (int e = t; e < J*DH; e += 256)
    qs[e] = qbuf[(size_t)(b*J + e/DH)*D + h*DH + (e%DH)];
  for (int e = t; e < cnt*DH; e += 256){
    int i = e/DH, d = e%DH;
    ks[e] = kv_act[(size_t)(off+i)*1024 + h*DH + d];
  }
  for (int i = t; i < cnt; i += 256){
    int n = act_idx[b*CAP+i]; sn[i] = n;
    const float* p = pc + ((size_t)b*NP+n)*6;
    pxyz[i*3] = p[0]; pxyz[i*3+1] = p[1]; pxyz[i*3+2] = p[2];
  }
  __syncthreads();
  for (int e = t; e < J*cnt; e += 256){
    int j = e/cnt, i = e%cnt;
    float acc = 0.f;
    for (int d = 0; d < DH; ++d) acc += qs[j*DH+d]*ks[i*DH+d];
    float bias;
    if (allm[b*J+j]) bias = (sn[i] == rescue[b*J+j]) ? 0.f : NEGF;
    else {
      float x0=sx[j*3], x1=sx[j*3+1], x2=sx[j*3+2];
      float p0=pxyz[i*3], p1=pxyz[i*3+1], p2=pxyz[i*3+2];
      float d2 = (x0*x0+x1*x1+x2*x2) + (p0*p0+p1*p1+p2*p2) - 2.f*(x0*p0+x1*p1+x2*p2);
      float dist = sqrtf(fmaxf(d2,0.f));
      float ar = c_scale[j]*0.1f;
      bias = (dist > ar) ? NEGF : 0.f;
    }
    ss[j*CAP+i] = acc*0.125f + bias;
  }
  __syncthreads();
  if (t < J){
    float m = -3.4e38f;
    for (int i = 0; i < cnt; ++i) m = fmaxf(m, ss[t*CAP+i]);
    float sum = 0.f;
    for (int i = 0; i < cnt; ++i){ float e_ = expf(ss[t*CAP+i]-m); ss[t*CAP+i] = e_; sum += e_; }
    float inv = 1.f/sum;
    for (int i = 0; i < cnt; ++i) ss[t*CAP+i] *= inv;
  }
  __syncthreads();
  for (int e = t; e < J*DH; e += 256){
    int j = e/DH, d = e%DH;
    float acc = 0.f;
    for (int i = 0; i < cnt; ++i)
      acc += ss[j*CAP+i]*kv_act[(size_t)(off+i)*1024 + 512 + h*DH + d];
    oh[(size_t)(b*J+j)*D + h*DH + d] = f2bf(acc);
  }
}

// ---------- final vel projection ----------
__global__ void k_vel(const float* __restrict__ x, const float* __restrict__ vel_w,
                      const float* __restrict__ vel_b, float* __restrict__ out){
  int r = blockIdx.x; int t = threadIdx.x; // 192
  int c = t >> 6; int lane = t & 63;
  float acc = 0.f;
  const float* xr = x + (size_t)r*D;
  for (int d = lane; d < D; d += 64) acc += xr[d]*vel_w[d*3+c];
  for (int s = 32; s > 0; s >>= 1) acc += __shfl_down(acc, s);
  if (lane == 0) out[r*3+c] = acc + vel_b[c];
}

// ============================================================================
static GemmArgs mk(const u16* A, const u16* Bt, const float* bias, const float* res,
                   float* Cf, u16* Ch, int M, int N, int K, int act, const int* Mdev, int TM){
  GemmArgs g; g.Ag=A; g.Bt=Bt; g.bias=bias; g.res=res; g.Cf=Cf; g.Ch=Ch;
  g.M=M; g.N=N; g.K=K; g.act=act; g.Mdev=Mdev;
  g.ntx=(M+TM-1)/TM; g.nwg=g.ntx*(N/64); return g;
}

extern "C" void kernel_launch(void* const* d_in, const int* in_sizes, int n_in,
                              void* d_out, int out_size, void* d_ws, size_t ws_size,
                              hipStream_t stream){
  const float* x_t        = (const float*)d_in[0];
  const float* t_in       = (const float*)d_in[1];
  const float* coarse     = (const float*)d_in[2];
  const float* radar      = (const float*)d_in[3];
  const float* pc_w       = (const float*)d_in[4];
  const float* pc_b       = (const float*)d_in[5];
  const float* coarse_w   = (const float*)d_in[6];
  const float* coarse_b   = (const float*)d_in[7];
  const float* state_w    = (const float*)d_in[8];
  const float* state_b    = (const float*)d_in[9];
  const float* jid_emb    = (const float*)d_in[10];
  const float* dop_w1     = (const float*)d_in[11];
  const float* dop_b1     = (const float*)d_in[12];
  const float* dop_w2     = (const float*)d_in[13];
  const float* dop_b2     = (const float*)d_in[14];
  const float* time_w1    = (const float*)d_in[15];
  const float* time_b1    = (const float*)d_in[16];
  const float* time_w2    = (const float*)d_in[17];
  const float* time_b2    = (const float*)d_in[18];
  const float* mod_w1     = (const float*)d_in[19];
  const float* mod_b1     = (const float*)d_in[20];
  const float* mod_w2     = (const float*)d_in[21];
  const float* mod_b2     = (const float*)d_in[22];
  const float* diff_w     = (const float*)d_in[23];
  const float* diff_b     = (const float*)d_in[24];
  const float* vel_w      = (const float*)d_in[25];
  const float* vel_b      = (const float*)d_in[26];
  const float* sa_qkv_w   = (const float*)d_in[27];
  const float* sa_qkv_b   = (const float*)d_in[28];
  const float* sa_out_w   = (const float*)d_in[29];
  const float* sa_out_b   = (const float*)d_in[30];
  const float* ca_qkv_w   = (const float*)d_in[31];
  const float* ca_qkv_b   = (const float*)d_in[32];
  const float* ca_out_w   = (const float*)d_in[33];
  const float* ca_out_b   = (const float*)d_in[34];
  const float* ff1_w      = (const float*)d_in[35];
  const float* ff1_b      = (const float*)d_in[36];
  const float* ff2_w      = (const float*)d_in[37];
  const float* ff2_b      = (const float*)d_in[38];
  const float* ln1_s      = (const float*)d_in[39];
  const float* ln1_b      = (const float*)d_in[40];
  const float* ln2_s      = (const float*)d_in[41];
  const float* ln2_b      = (const float*)d_in[42];
  const float* ln3_s      = (const float*)d_in[43];
  const float* ln3_b      = (const float*)d_in[44];
  (void)in_sizes; (void)n_in; (void)out_size; (void)ws_size;

  const int R = NB*J; // 1728

  char* wp = (char*)d_ws;
  auto alloc = [&](size_t bytes)->void*{
    void* r = (void*)wp;
    wp += (bytes + 255) & ~(size_t)255;
    return r;
  };
  float*        denom_sum = (float*)alloc(R*4);
  int*          rescue    = (int*)  alloc(R*4);
  int*          allm      = (int*)  alloc(R*4);
  unsigned int* bitmap    = (unsigned int*)alloc(NB*(NP/32)*4);
  int*          act_idx   = (int*)  alloc(NB*CAP*4);
  int*          act_cnt   = (int*)  alloc(NB*4);
  int*          act_off   = (int*)  alloc(NB*4);
  int*          act_total = (int*)  alloc(64);
  float* Gp       = (float*)alloc((size_t)NB*GCH*J*64*4);
  float* h_dop    = (float*)alloc((size_t)R*D*4);
  float* h_state  = (float*)alloc((size_t)R*D*4);
  float* h_coarse = (float*)alloc((size_t)R*D*4);
  float* hstruct  = (float*)alloc((size_t)R*D*4);
  float* xres     = (float*)alloc((size_t)R*D*4);
  float* qbuf     = (float*)alloc((size_t)R*D*4);
  float* h_time   = (float*)alloc((size_t)NB*D*4);
  float* mod2     = (float*)alloc((size_t)R*2*D*4);
  float* qkv      = (float*)alloc((size_t)R*3*D*4);
  float* kv_act   = (float*)alloc((size_t)NB*CAP*2*D*4);   // stage-1 aliases hs2
  u16* hsh   = (u16*)alloc((size_t)R*D*2);
  u16* hbufh = (u16*)alloc((size_t)R*D*2);
  u16* attnoh= (u16*)alloc((size_t)R*D*2);
  u16* ffhh  = (u16*)alloc((size_t)R*DFF*2);
  u16* mah   = (u16*)alloc((size_t)NB*CAP*D*2);
  u16* time_w2t = (u16*)alloc((size_t)512*512*2);
  u16* mod_w1t  = (u16*)alloc((size_t)1024*512*2);
  u16* mod_w2t  = (u16*)alloc((size_t)1024*1024*2);
  u16* diff_wt  = (u16*)alloc((size_t)512*1024*2);
  u16* sa_qkv_t = (u16*)alloc((size_t)NLAYER*1536*512*2);
  u16* sa_out_t = (u16*)alloc((size_t)NLAYER*512*512*2);
  u16* ca_qkv_t = (u16*)alloc((size_t)NLAYER*1536*512*2);
  u16* ca_out_t = (u16*)alloc((size_t)NLAYER*512*512*2);
  u16* ff1_t    = (u16*)alloc((size_t)NLAYER*2048*512*2);
  u16* ff2_t    = (u16*)alloc((size_t)NLAYER*512*2048*2);
  // stage-1-only aliases
  u16* thh   = attnoh;
  u16* mod1h = ffhh;
  u16* hs2h  = (u16*)kv_act;

  // ---- single-launch weight conversion ----
  {
    WcTab tab;
    int s = 0;
    auto set = [&](int i, const float* src, u16* dst, int K, int N, int L){
      tab.d[i].src = src; tab.d[i].dst = dst; tab.d[i].K = K; tab.d[i].N = N;
      tab.d[i].tk = K/64; tab.d[i].tn = N/64; tab.d[i].L = L; tab.d[i].start = s;
      s += (K/64)*(N/64)*L;
    };
    set(0, time_w2, time_w2t, 512, 512, 1);
    set(1, mod_w1,  mod_w1t,  512, 1024, 1);
    set(2, mod_w2,  mod_w2t,  1024, 1024, 1);
    set(3, diff_w,  diff_wt,  1024, 512, 1);
    set(4, sa_qkv_w, sa_qkv_t, 512, 1536, NLAYER);
    set(5, sa_out_w, sa_out_t, 512, 512, NLAYER);
    set(6, ca_qkv_w, ca_qkv_t, 512, 1536, NLAYER);
    set(7, ca_out_w, ca_out_t, 512, 512, NLAYER);
    set(8, ff1_w,    ff1_t,    512, 2048, NLAYER);
    set(9, ff2_w,    ff2_t,    2048, 512, NLAYER);
    k_wconv_all<<<s, 256, 0, stream>>>(tab);
  }

  // ---- stage 0 ----
  hipMemsetAsync(bitmap, 0, NB*(NP/32)*4, stream);
  k_perj<<<R, 256, 0, stream>>>(x_t, radar, denom_sum, rescue, allm, bitmap);
  k_compact<<<1, 1024, 0, stream>>>(bitmap, act_idx, act_cnt, act_off, act_total);
  k_gpart<<<dim3(NB, GCH), 256, 0, stream>>>(x_t, radar, dop_w1, dop_b1, Gp);
  k_hdop2<<<dim3(NB, 2), 256, 0, stream>>>(Gp, dop_w2, dop_b2, denom_sum, h_dop);

  // ---- stage 1 ----
  k_stage1<<<(4*R*D + NB*D + 255)/256, 256, 0, stream>>>(
      x_t, state_w, state_b, coarse, coarse_w, coarse_b, t_in, time_w1, time_b1,
      h_state, hsh, h_coarse, thh, hs2h);
  { GemmArgs ga = mk(thh, time_w2t, time_b2, nullptr, h_time, nullptr, NB, 512, 512, 0, nullptr, 32);
    GemmArgs gb = mk(hsh, mod_w1t, mod_b1, nullptr, nullptr, mod1h, R, 1024, 512, 1, nullptr, 32);
    k_gemm_dual<32,32><<<ga.nwg + gb.nwg, 256, 0, stream>>>(ga, gb); }
  { GemmArgs ga = mk(mod1h, mod_w2t, mod_b2, nullptr, mod2, nullptr, R, 1024, 1024, 0, nullptr, 32);
    GemmArgs gb = mk(hs2h, diff_wt, diff_b, nullptr, hstruct, nullptr, R, 512, 1024, 0, nullptr, 32);
    k_gemm_dual<32,32><<<ga.nwg + gb.nwg, 256, 0, stream>>>(ga, gb); }
  k_query<<<(R*D+255)/256, 256, 0, stream>>>(h_coarse, h_time, h_dop, h_state, hstruct,
                                             jid_emb, mod2, xres);
  k_memact<<<NB*CAP, 128, 0, stream>>>(x_t, radar, pc_w, pc_b, act_idx, act_cnt, act_off, mah);

  // ---- stage 2: transformer layers ----
  for (int l = 0; l < NLAYER; ++l){
    k_ln<<<R, 256, 0, stream>>>(xres, ln1_s + l*D, ln1_b + l*D, hbufh);
    { GemmArgs g = mk(hbufh, sa_qkv_t + (size_t)l*1536*512, sa_qkv_b + l*1536, nullptr,
                      qkv, nullptr, R, 1536, 512, 0, nullptr, 32);
      k_gemm<32><<<g.nwg, 256, 0, stream>>>(g); }
    k_selfattn<<<NB*H, 256, 0, stream>>>(qkv, attnoh);
    { GemmArgs g = mk(attnoh, sa_out_t + (size_t)l*512*512, sa_out_b + l*D, xres,
                      xres, nullptr, R, 512, 512, 0, nullptr, 32);
      k_gemm<32><<<g.nwg, 256, 0, stream>>>(g); }

    k_ln<<<R, 256, 0, stream>>>(xres, ln2_s + l*D, ln2_b + l*D, hbufh);
    { GemmArgs ga = mk(hbufh, ca_qkv_t + (size_t)l*1536*512, ca_qkv_b + l*1536, nullptr,
                       qbuf, nullptr, R, 512, 512, 0, nullptr, 32);
      GemmArgs gb = mk(mah, ca_qkv_t + (size_t)l*1536*512 + (size_t)512*512,
                       ca_qkv_b + l*1536 + 512, nullptr,
                       kv_act, nullptr, NB*CAP, 1024, 512, 0, act_total, 64);
      k_gemm_dual<32,64><<<ga.nwg + gb.nwg, 256, 0, stream>>>(ga, gb); }
    k_crossattn<<<NB*H, 256, 0, stream>>>(qbuf, kv_act, x_t, radar, act_idx, act_cnt,
                                          act_off, rescue, allm, attnoh);
    { GemmArgs g = mk(attnoh, ca_out_t + (size_t)l*512*512, ca_out_b + l*D, xres,
                      xres, nullptr, R, 512, 512, 0, nullptr, 32);
      k_gemm<32><<<g.nwg, 256, 0, stream>>>(g); }

    k_ln<<<R, 256, 0, stream>>>(xres, ln3_s + l*D, ln3_b + l*D, hbufh);
    { GemmArgs g = mk(hbufh, ff1_t + (size_t)l*2048*512, ff1_b + l*DFF, nullptr,
                      nullptr, ffhh, R, 2048, 512, 2, nullptr, 32);
      k_gemm<32><<<g.nwg, 256, 0, stream>>>(g); }
    { GemmArgs g = mk(ffhh, ff2_t + (size_t)l*512*2048, ff2_b + l*D, xres,
                      xres, nullptr, R, 512, 2048, 0, nullptr, 32);
      k_gemm<32><<<g.nwg, 256, 0, stream>>>(g); }
  }

  k_vel<<<R, 192, 0, stream>>>(xres, vel_w, vel_b, (float*)d_out);
}